// Round 8
// baseline (286.076 us; speedup 1.0000x reference)
//
#include <hip/hip_runtime.h>
#include <hip/hip_bf16.h>

// X = Z * G, G = (I - tril(A_raw,-1))^{-1} (unit lower-triangular 256x256)
// Z: [131072 x 256] fp32, Out: [131072 x 256] fp32.
//
// make_G3 (unchanged): 256 blocks, right-looking solve, readlane broadcast.
// scm_gemm9: OCCUPANCY kernel. R6 showed distance-4 asm pipeline works but
//   4 waves/SIMD (64 KB LDS -> 2 blocks/CU) leaves ~90% of wave-phase slots
//   empty. Split N in 4 (Gs = 64 cols x 256 K = 32 KB) -> 4 blocks/CU =
//   8 waves/SIMD. acc halves to 16 VGPR, distance-2 pipeline (zf[4]) fits
//   the ~60-VGPR working set into the 64-VGPR/8-wave tier.
//   Z is read 4x logically: all 4 N-quarters of an M-panel are placed on the
//   SAME XCD (blocks 8 apart under round-robin dispatch) so 3 reads hit the
//   XCD L2 (panel 512 KB << 4 MB L2). Counted vmcnt: iter0 = 2; steady
//   q<2 = 18 (16 stores + 2 loads newer), q>=2 = 2; T=31 = 0.

typedef __bf16 bf16x8 __attribute__((ext_vector_type(8)));
typedef float f32x4 __attribute__((ext_vector_type(4)));

__device__ __forceinline__ unsigned short f2bf(float f) {
    union { float f; unsigned u; } v; v.f = f;
    unsigned u = v.u;
    u += 0x7FFFu + ((u >> 16) & 1u);   // RNE
    return (unsigned short)(u >> 16);
}
__device__ __forceinline__ bf16x8 pack8(float4 a, float4 b) {
    union { bf16x8 v; __hip_bfloat162 h[4]; } u;
    u.h[0] = __float22bfloat162_rn(make_float2(a.x, a.y));
    u.h[1] = __float22bfloat162_rn(make_float2(a.z, a.w));
    u.h[2] = __float22bfloat162_rn(make_float2(b.x, b.y));
    u.h[3] = __float22bfloat162_rn(make_float2(b.z, b.w));
    return u.v;
}

// ---------------------------------------------------------------------------
// Kernel 1: G columns, one block per column (unchanged).
// ---------------------------------------------------------------------------
#define AST 258
__global__ __launch_bounds__(256) void make_G3(const float* __restrict__ A,
                                               unsigned short* __restrict__ Gt) {
    __shared__ unsigned short As[256 * AST];   // 129 KB
    const int tid = threadIdx.x;
    const int l = tid & 63;
    const int wv = tid >> 6;

    for (int it = 0; it < 64; ++it) {
        const int r = it * 4 + wv;
        const int c0 = l * 4;
        float4 v = *(const float4*)(A + r * 256 + c0);
        *(ushort2*)(&As[r * AST + c0])     = make_ushort2(f2bf(v.x), f2bf(v.y));
        *(ushort2*)(&As[r * AST + c0 + 2]) = make_ushort2(f2bf(v.z), f2bf(v.w));
    }
    __syncthreads();
    if (wv != 0) return;

    const int c = blockIdx.x;
    float p[4];
#pragma unroll
    for (int k = 0; k < 4; ++k) p[k] = (64 * k + l == c) ? 1.f : 0.f;

#pragma unroll
    for (int kb = 0; kb < 4; ++kb) {
#pragma unroll 8
        for (int i2 = 0; i2 < 32; ++i2) {
            unsigned u[4];
#pragma unroll
            for (int k = 0; k < 4; ++k)
                if (k >= kb)
                    u[k] = *(const unsigned*)(&As[(64 * k + l) * AST + kb * 64 + 2 * i2]);
            const int t0 = 2 * i2, t1 = t0 + 1;
            float s0 = __int_as_float(__builtin_amdgcn_readlane(__float_as_int(p[kb]), t0));
            p[kb] += (l > t0 ? __int_as_float(u[kb] << 16) : 0.f) * s0;
#pragma unroll
            for (int k = 0; k < 4; ++k)
                if (k > kb) p[k] += __int_as_float(u[k] << 16) * s0;
            float s1 = __int_as_float(__builtin_amdgcn_readlane(__float_as_int(p[kb]), t1));
            p[kb] += (l > t1 ? __int_as_float(u[kb] & 0xffff0000u) : 0.f) * s1;
#pragma unroll
            for (int k = 0; k < 4; ++k)
                if (k > kb) p[k] += __int_as_float(u[k] & 0xffff0000u) * s1;
        }
    }
#pragma unroll
    for (int k = 0; k < 4; ++k)
        Gt[c * 256 + 64 * k + l] = f2bf(p[k]);
}

// ---------------------------------------------------------------------------
// Kernel 2: Out = Z @ G. 1024 blocks (256 M-panels x 4 N-quarters) x 512 thr.
// ---------------------------------------------------------------------------
// Linear phase T (0..31): iter = T>>3, sub-phase q = T&7, pair slot = T&1.
// Consumes the pair issued at T-2 (or prologue); prefetches for T+2.
template<int T>
__device__ __forceinline__ void phaseT(float4& a0, float4& a1,
                                       const float* zbase, f32x4 acc[4],
                                       const unsigned short* Gsp,
                                       int n, int quad, int swz) {
    constexpr int q = T & 7;
    constexpr int CNT = (T < 8)   ? 2
                      : (T == 31) ? 0
                      : (q < 2 ? 18 : 2);
    asm volatile("s_waitcnt vmcnt(%0)" :: "n"(CNT) : "memory");
    __builtin_amdgcn_sched_barrier(0);           // pin pack/MFMA below wait
    bf16x8 af = pack8(a0, a1);
    if constexpr (T + 2 < 32) {
        constexpr int TT = T + 2;
        const float* pz = zbase + (size_t)(TT >> 3) * 32768;
        asm volatile("global_load_dwordx4 %0, %1, off offset:%2"
                     : "=v"(a0) : "v"(pz), "n"((TT & 7) * 128));
        asm volatile("global_load_dwordx4 %0, %1, off offset:%2"
                     : "=v"(a1) : "v"(pz), "n"((TT & 7) * 128 + 16));
    }
#pragma unroll
    for (int nt = 0; nt < 4; ++nt) {
        const bf16x8 b = *(const bf16x8*)(
            &Gsp[(nt * 16 + n) * 256 + ((q * 4 + quad) ^ swz) * 8]);
        acc[nt] = __builtin_amdgcn_mfma_f32_16x16x32_bf16(af, b, acc[nt], 0, 0, 0);
    }
}

__global__ __launch_bounds__(512, 4) void scm_gemm9(const float* __restrict__ Z,
                                                    const unsigned short* __restrict__ Gt,
                                                    float* __restrict__ Out) {
    __shared__ __align__(16) unsigned short Gs[64 * 256];    // 32 KB
    const int tid = threadIdx.x;
    const int lane = tid & 63;
    const int wave = tid >> 6;
    const int n = lane & 15;
    const int quad = lane >> 4;
    // XCD co-location: b = 32g + 8j + x. XCD = x (round-robin dispatch),
    // N-quarter = j, M-panel m = 8g + x. All 4 quarters of panel m share
    // XCD x -> Z panel (512 KB) served from that XCD's L2 after 1st fetch.
    const int bn = ((blockIdx.x >> 3) & 3) * 64;
    const size_t blockRow = (size_t)((blockIdx.x >> 5) * 8 + (blockIdx.x & 7)) * 512;

    // ---- stage G quarter (32 KB): 2048 granules / 512 thr = 4 each ----
#pragma unroll
    for (int it = 0; it < 4; ++it) {
        const int chunk = it * 512 + tid;
        const int row = chunk >> 5;            // local col 0..63
        const int g = chunk & 31;
        const int gs = g ^ (row & 7);
        uint4 v = *(const uint4*)(Gt + (bn + row) * 256 + g * 8);
        *(uint4*)(&Gs[row * 256 + gs * 8]) = v;
    }
    __syncthreads();   // compiler drains vmcnt/lgkmcnt here -> outstanding = 0

    const int swz = n & 7;
    const float* zbase = Z + (blockRow + wave * 16 + n) * 256 + quad * 8;
    float* obase = Out + (blockRow + wave * 16 + quad * 4) * 256 + bn + n;

    f32x4 acc[4];
#pragma unroll
    for (int nt = 0; nt < 4; ++nt) {
        f32x4 zero = {0.f, 0.f, 0.f, 0.f};
        acc[nt] = zero;
    }

    // 2 pairs = 4 float4 = 16 VGPR rotation buffer (distance-2).
    float4 zf[4];
    // ---- prologue: pairs for phases 0,1 ----
    asm volatile("global_load_dwordx4 %0, %1, off offset:0"   : "=v"(zf[0]) : "v"(zbase));
    asm volatile("global_load_dwordx4 %0, %1, off offset:16"  : "=v"(zf[1]) : "v"(zbase));
    asm volatile("global_load_dwordx4 %0, %1, off offset:128" : "=v"(zf[2]) : "v"(zbase));
    asm volatile("global_load_dwordx4 %0, %1, off offset:144" : "=v"(zf[3]) : "v"(zbase));

#define PH(T) phaseT<T>(zf[2 * ((T) & 1)], zf[2 * ((T) & 1) + 1], zbase, acc, Gs, n, quad, swz)
#define STORE_ITER(i, REZERO)                                              \
    {                                                                      \
        asm volatile("" ::: "memory");                                     \
        float* oi = obase + (size_t)(i) * 32768;                           \
        _Pragma("unroll")                                                  \
        for (int nt = 0; nt < 4; ++nt)                                     \
            _Pragma("unroll")                                              \
            for (int r = 0; r < 4; ++r) {                                  \
                oi[(size_t)r * 256 + nt * 16] = acc[nt][r];                \
                if (REZERO) acc[nt][r] = 0.f;                              \
            }                                                              \
        asm volatile("" ::: "memory");                                     \
    }

    PH(0);  PH(1);  PH(2);  PH(3);  PH(4);  PH(5);  PH(6);  PH(7);
    STORE_ITER(0, true);
    PH(8);  PH(9);  PH(10); PH(11); PH(12); PH(13); PH(14); PH(15);
    STORE_ITER(1, true);
    PH(16); PH(17); PH(18); PH(19); PH(20); PH(21); PH(22); PH(23);
    STORE_ITER(2, true);
    PH(24); PH(25); PH(26); PH(27); PH(28); PH(29); PH(30); PH(31);
    STORE_ITER(3, false);

#undef PH
#undef STORE_ITER
}

extern "C" void kernel_launch(void* const* d_in, const int* in_sizes, int n_in,
                              void* d_out, int out_size, void* d_ws, size_t ws_size,
                              hipStream_t stream) {
    const float* Z = (const float*)d_in[0];       // [131072 x 256]
    const float* A = (const float*)d_in[1];       // [256 x 256]
    float* Out = (float*)d_out;                   // [131072 x 256]
    unsigned short* Gt = (unsigned short*)d_ws;   // 256*256 bf16 = 128 KB

    hipLaunchKernelGGL(make_G3, dim3(256), dim3(256), 0, stream, A, Gt);
    hipLaunchKernelGGL(scm_gemm9, dim3(1024), dim3(512), 0, stream, Z, Gt, Out);
}

// Round 9
// 281.471 us; speedup vs baseline: 1.0164x; 1.0164x over previous
//
#include <hip/hip_runtime.h>
#include <hip/hip_bf16.h>

// X = Z * G, G = (I - tril(A_raw,-1))^{-1} (unit lower-triangular 256x256)
// Z: [131072 x 256] fp32, Out: [131072 x 256] fp32.
//
// make_G3 (unchanged): 256 blocks, right-looking solve, readlane broadcast.
// scm_gemm10 = gemm9's occupancy geometry (1024 blocks = 256 M x 4 N-quarters,
//   32 KB Gs -> 4 blocks/CU, 8 waves/SIMD; XCD co-location: FETCH halved to
//   67 MB in R8 -> keep) + gemm8's PROVEN distance-4 pipeline (R8's distance-2
//   gave only ~180cy cover < L2 latency -> BW collapsed to 1.8 TB/s).
//   zf[8] = 4 pairs cycling period 4: phase T consumes pair issued at T-4,
//   reissues for T+4. In-flight: 8 loads/wave x 32 waves/CU = 256.
//   Counted vmcnt (FIFO over ALL VMEM; pair for T issued at T-4; newer =
//   3 pairs + 16 stores iff store-block intervened):
//     iter0 (T<8) -> 6; steady q<4 -> 22, q>=4 -> 6; tail T=29/30/31 -> 4/2/0.
//   VGPR budget: acc 16 + zf 32 + af/addr ~12 = ~60 <= 64 (8-wave tier).

typedef __bf16 bf16x8 __attribute__((ext_vector_type(8)));
typedef float f32x4 __attribute__((ext_vector_type(4)));

__device__ __forceinline__ unsigned short f2bf(float f) {
    union { float f; unsigned u; } v; v.f = f;
    unsigned u = v.u;
    u += 0x7FFFu + ((u >> 16) & 1u);   // RNE
    return (unsigned short)(u >> 16);
}
__device__ __forceinline__ bf16x8 pack8(float4 a, float4 b) {
    union { bf16x8 v; __hip_bfloat162 h[4]; } u;
    u.h[0] = __float22bfloat162_rn(make_float2(a.x, a.y));
    u.h[1] = __float22bfloat162_rn(make_float2(a.z, a.w));
    u.h[2] = __float22bfloat162_rn(make_float2(b.x, b.y));
    u.h[3] = __float22bfloat162_rn(make_float2(b.z, b.w));
    return u.v;
}

// ---------------------------------------------------------------------------
// Kernel 1: G columns, one block per column (unchanged).
// ---------------------------------------------------------------------------
#define AST 258
__global__ __launch_bounds__(256) void make_G3(const float* __restrict__ A,
                                               unsigned short* __restrict__ Gt) {
    __shared__ unsigned short As[256 * AST];   // 129 KB
    const int tid = threadIdx.x;
    const int l = tid & 63;
    const int wv = tid >> 6;

    for (int it = 0; it < 64; ++it) {
        const int r = it * 4 + wv;
        const int c0 = l * 4;
        float4 v = *(const float4*)(A + r * 256 + c0);
        *(ushort2*)(&As[r * AST + c0])     = make_ushort2(f2bf(v.x), f2bf(v.y));
        *(ushort2*)(&As[r * AST + c0 + 2]) = make_ushort2(f2bf(v.z), f2bf(v.w));
    }
    __syncthreads();
    if (wv != 0) return;

    const int c = blockIdx.x;
    float p[4];
#pragma unroll
    for (int k = 0; k < 4; ++k) p[k] = (64 * k + l == c) ? 1.f : 0.f;

#pragma unroll
    for (int kb = 0; kb < 4; ++kb) {
#pragma unroll 8
        for (int i2 = 0; i2 < 32; ++i2) {
            unsigned u[4];
#pragma unroll
            for (int k = 0; k < 4; ++k)
                if (k >= kb)
                    u[k] = *(const unsigned*)(&As[(64 * k + l) * AST + kb * 64 + 2 * i2]);
            const int t0 = 2 * i2, t1 = t0 + 1;
            float s0 = __int_as_float(__builtin_amdgcn_readlane(__float_as_int(p[kb]), t0));
            p[kb] += (l > t0 ? __int_as_float(u[kb] << 16) : 0.f) * s0;
#pragma unroll
            for (int k = 0; k < 4; ++k)
                if (k > kb) p[k] += __int_as_float(u[k] << 16) * s0;
            float s1 = __int_as_float(__builtin_amdgcn_readlane(__float_as_int(p[kb]), t1));
            p[kb] += (l > t1 ? __int_as_float(u[kb] & 0xffff0000u) : 0.f) * s1;
#pragma unroll
            for (int k = 0; k < 4; ++k)
                if (k > kb) p[k] += __int_as_float(u[k] & 0xffff0000u) * s1;
        }
    }
#pragma unroll
    for (int k = 0; k < 4; ++k)
        Gt[c * 256 + 64 * k + l] = f2bf(p[k]);
}

// ---------------------------------------------------------------------------
// Kernel 2: Out = Z @ G. 1024 blocks (256 M-panels x 4 N-quarters) x 512 thr.
// ---------------------------------------------------------------------------
// Linear phase T (0..31): iter = T>>3, sub-phase q = T&7, pair slot = T&3.
// Consumes the pair issued at T-4 (or prologue); prefetches for T+4.
template<int T>
__device__ __forceinline__ void phaseT(float4& a0, float4& a1,
                                       const float* zbase, f32x4 acc[4],
                                       const unsigned short* Gsp,
                                       int n, int quad, int swz) {
    constexpr int q = T & 7;
    constexpr int CNT = (T < 8)   ? 6
                      : (T == 29) ? 4
                      : (T == 30) ? 2
                      : (T == 31) ? 0
                      : (q < 4 ? 22 : 6);
    asm volatile("s_waitcnt vmcnt(%0)" :: "n"(CNT) : "memory");
    __builtin_amdgcn_sched_barrier(0);           // pin pack/MFMA below wait
    bf16x8 af = pack8(a0, a1);
    if constexpr (T + 4 < 32) {
        constexpr int TT = T + 4;
        const float* pz = zbase + (size_t)(TT >> 3) * 32768;
        asm volatile("global_load_dwordx4 %0, %1, off offset:%2"
                     : "=v"(a0) : "v"(pz), "n"((TT & 7) * 128));
        asm volatile("global_load_dwordx4 %0, %1, off offset:%2"
                     : "=v"(a1) : "v"(pz), "n"((TT & 7) * 128 + 16));
    }
#pragma unroll
    for (int nt = 0; nt < 4; ++nt) {
        const bf16x8 b = *(const bf16x8*)(
            &Gsp[(nt * 16 + n) * 256 + ((q * 4 + quad) ^ swz) * 8]);
        acc[nt] = __builtin_amdgcn_mfma_f32_16x16x32_bf16(af, b, acc[nt], 0, 0, 0);
    }
}

__global__ __launch_bounds__(512, 4) void scm_gemm10(const float* __restrict__ Z,
                                                     const unsigned short* __restrict__ Gt,
                                                     float* __restrict__ Out) {
    __shared__ __align__(16) unsigned short Gs[64 * 256];    // 32 KB
    const int tid = threadIdx.x;
    const int lane = tid & 63;
    const int wave = tid >> 6;
    const int n = lane & 15;
    const int quad = lane >> 4;
    // XCD co-location: b = 32g + 8j + x. XCD = x (round-robin dispatch),
    // N-quarter = j, M-panel m = 8g + x. All 4 quarters of panel m share
    // XCD x -> Z panel (512 KB) served from that XCD's L2 after 1st fetch.
    // (R8 evidence: FETCH_SIZE 132 -> 67 MB.)
    const int bn = ((blockIdx.x >> 3) & 3) * 64;
    const size_t blockRow = (size_t)((blockIdx.x >> 5) * 8 + (blockIdx.x & 7)) * 512;

    // ---- stage G quarter (32 KB): 2048 granules / 512 thr = 4 each ----
#pragma unroll
    for (int it = 0; it < 4; ++it) {
        const int chunk = it * 512 + tid;
        const int row = chunk >> 5;            // local col 0..63
        const int g = chunk & 31;
        const int gs = g ^ (row & 7);
        uint4 v = *(const uint4*)(Gt + (bn + row) * 256 + g * 8);
        *(uint4*)(&Gs[row * 256 + gs * 8]) = v;
    }
    __syncthreads();   // compiler drains vmcnt/lgkmcnt here -> outstanding = 0

    const int swz = n & 7;
    const float* zbase = Z + (blockRow + wave * 16 + n) * 256 + quad * 8;
    float* obase = Out + (blockRow + wave * 16 + quad * 4) * 256 + bn + n;

    f32x4 acc[4];
#pragma unroll
    for (int nt = 0; nt < 4; ++nt) {
        f32x4 zero = {0.f, 0.f, 0.f, 0.f};
        acc[nt] = zero;
    }

    // 4 pairs = 8 float4 = 32 VGPR rotation buffer (distance-4).
    float4 zf[8];
    // ---- prologue: pairs for phases 0..3 (iter 0, k-granule groups 0..3) ----
    asm volatile("global_load_dwordx4 %0, %1, off offset:0"   : "=v"(zf[0]) : "v"(zbase));
    asm volatile("global_load_dwordx4 %0, %1, off offset:16"  : "=v"(zf[1]) : "v"(zbase));
    asm volatile("global_load_dwordx4 %0, %1, off offset:128" : "=v"(zf[2]) : "v"(zbase));
    asm volatile("global_load_dwordx4 %0, %1, off offset:144" : "=v"(zf[3]) : "v"(zbase));
    asm volatile("global_load_dwordx4 %0, %1, off offset:256" : "=v"(zf[4]) : "v"(zbase));
    asm volatile("global_load_dwordx4 %0, %1, off offset:272" : "=v"(zf[5]) : "v"(zbase));
    asm volatile("global_load_dwordx4 %0, %1, off offset:384" : "=v"(zf[6]) : "v"(zbase));
    asm volatile("global_load_dwordx4 %0, %1, off offset:400" : "=v"(zf[7]) : "v"(zbase));

#define PH(T) phaseT<T>(zf[2 * ((T) & 3)], zf[2 * ((T) & 3) + 1], zbase, acc, Gs, n, quad, swz)
#define STORE_ITER(i, REZERO)                                              \
    {                                                                      \
        asm volatile("" ::: "memory");                                     \
        float* oi = obase + (size_t)(i) * 32768;                           \
        _Pragma("unroll")                                                  \
        for (int nt = 0; nt < 4; ++nt)                                     \
            _Pragma("unroll")                                              \
            for (int r = 0; r < 4; ++r) {                                  \
                oi[(size_t)r * 256 + nt * 16] = acc[nt][r];                \
                if (REZERO) acc[nt][r] = 0.f;                              \
            }                                                              \
        asm volatile("" ::: "memory");                                     \
    }

    PH(0);  PH(1);  PH(2);  PH(3);  PH(4);  PH(5);  PH(6);  PH(7);
    STORE_ITER(0, true);
    PH(8);  PH(9);  PH(10); PH(11); PH(12); PH(13); PH(14); PH(15);
    STORE_ITER(1, true);
    PH(16); PH(17); PH(18); PH(19); PH(20); PH(21); PH(22); PH(23);
    STORE_ITER(2, true);
    PH(24); PH(25); PH(26); PH(27); PH(28); PH(29); PH(30); PH(31);
    STORE_ITER(3, false);

#undef PH
#undef STORE_ITER
}

extern "C" void kernel_launch(void* const* d_in, const int* in_sizes, int n_in,
                              void* d_out, int out_size, void* d_ws, size_t ws_size,
                              hipStream_t stream) {
    const float* Z = (const float*)d_in[0];       // [131072 x 256]
    const float* A = (const float*)d_in[1];       // [256 x 256]
    float* Out = (float*)d_out;                   // [131072 x 256]
    unsigned short* Gt = (unsigned short*)d_ws;   // 256*256 bf16 = 128 KB

    hipLaunchKernelGGL(make_G3, dim3(256), dim3(256), 0, stream, A, Gt);
    hipLaunchKernelGGL(scm_gemm10, dim3(1024), dim3(512), 0, stream, Z, Gt, Out);
}